// Round 9
// baseline (463.613 us; speedup 1.0000x reference)
//
#include <hip/hip_runtime.h>
#include <math.h>

// x [B=512, C=1024, H=8, W=8] f32. out same shape.
#define C_DIM 1024
#define HW 64
#define F4B 16384           // float4 per batch
#define QF4 4096            // float4 per quarter batch
#define EPSV 1e-8f
#define TINYF 1.17549435e-38f

typedef float f32x4_t __attribute__((ext_vector_type(4)));

__device__ __forceinline__ float devload(const float* p) {
    return __hip_atomic_load(p, __ATOMIC_RELAXED, __HIP_MEMORY_SCOPE_AGENT);
}

__device__ __forceinline__ void threefry2x32_01(unsigned x0, unsigned x1,
                                                unsigned& o0, unsigned& o1) {
    const unsigned ks0 = 0u, ks1 = 1u, ks2 = 0x1BD11BDBu; // 0x1BD11BDA ^ 0 ^ 1
    x0 += ks0; x1 += ks1;
#define TF_R(r) { x0 += x1; x1 = (x1 << (r)) | (x1 >> (32 - (r))); x1 ^= x0; }
    TF_R(13) TF_R(15) TF_R(26) TF_R(6)
    x0 += ks1; x1 += ks2 + 1u;
    TF_R(17) TF_R(29) TF_R(16) TF_R(24)
    x0 += ks2; x1 += ks0 + 2u;
    TF_R(13) TF_R(15) TF_R(26) TF_R(6)
    x0 += ks0; x1 += ks1 + 3u;
    TF_R(17) TF_R(29) TF_R(16) TF_R(24)
    x0 += ks1; x1 += ks2 + 4u;
    TF_R(13) TF_R(15) TF_R(26) TF_R(6)
    x0 += ks2; x1 += ks0 + 5u;
#undef TF_R
    o0 = x0; o1 = x1;
}

// jax_threefry_partitionable=True: counter (hi=0, lo=n), out = o0 ^ o1.
__device__ __forceinline__ unsigned jax_random_bits(unsigned n) {
    unsigned o0, o1;
    threefry2x32_01(0u, n, o0, o1);
    return o0 ^ o1;
}

__device__ __forceinline__ float gumbel01(unsigned n) {
    unsigned bits = jax_random_bits(n);
    float f = __uint_as_float(0x3F800000u | (bits >> 9)) - 1.0f;
    float u = fmaxf(TINYF, f + TINYF);
    return -logf(-logf(u));
}

__device__ __forceinline__ bool bad_val(float v) {
    return ((__float_as_uint(v) & 0x7F800000u) == 0x7F800000u) || (v < 0.0f);
}

// -------------- Single-dispatch, per-batch spin-synced, fill-shaped ---------
// Grid 2048 x 256, __launch_bounds__(256,8): VGPR<=64 -> 8 blocks/CU -> the
// ENTIRE grid is co-resident (2048 = 256 CU x 8). Block bid owns quarter
// (b = bid>>2, q = bid&3):
//   P1 partial channel max -> part[b][q][64]; fence; atomicAdd(cnt[b]).
//   Spin until cnt[b]==4 (device-scope; batches proceed independently, so
//   early batches WRITE while late batches READ -> streams overlap at 32
//   waves/CU, unlike the phase-lockstep r8 structure).
//   Each of the 4 blocks redundantly computes the deterministic middle ->
//   gate in LDS; applies its own quarter (L2-warm re-read, nt store).
__global__ __launch_bounds__(256, 8) void sa_onepass_kernel(
    const float* __restrict__ x,
    const float* __restrict__ w11,
    const float* __restrict__ w5,
    const float* __restrict__ b5,
    const float* __restrict__ w6,
    const float* __restrict__ b6,
    float* __restrict__ out,
    int* __restrict__ cnt,
    float* __restrict__ part)
{
    const int bid = blockIdx.x;
    const int t = threadIdx.x;
    const int b = bid >> 2, q = bid & 3;

    const float4* __restrict__ xq = (const float4*)x + (size_t)b * F4B + (size_t)q * QF4;
    float4* __restrict__ oq = (float4*)out + (size_t)b * F4B + (size_t)q * QF4;

    __shared__ float4 red[4 * 16];
    __shared__ float sm[64], sa16[16], sb16[16], so2[64], shid[4 * 64];
    __shared__ __align__(16) float sgate[64];

    // ---- P1: streaming partial channel max over this 64 KB quarter ----
    // Thread t covers f4 idx t + 256*i -> hw4 group t&15 fixed.
    float4 pm = make_float4(-INFINITY, -INFINITY, -INFINITY, -INFINITY);
#pragma unroll
    for (int i = 0; i < 16; ++i) {
        float4 v = xq[t + 256 * i];
        pm.x = fmaxf(pm.x, v.x); pm.y = fmaxf(pm.y, v.y);
        pm.z = fmaxf(pm.z, v.z); pm.w = fmaxf(pm.w, v.w);
    }
#pragma unroll
    for (int off = 16; off <= 32; off <<= 1) {
        pm.x = fmaxf(pm.x, __shfl_xor(pm.x, off, 64));
        pm.y = fmaxf(pm.y, __shfl_xor(pm.y, off, 64));
        pm.z = fmaxf(pm.z, __shfl_xor(pm.z, off, 64));
        pm.w = fmaxf(pm.w, __shfl_xor(pm.w, off, 64));
    }
    const int wv = t >> 6, lane = t & 63;
    if (lane < 16) red[wv * 16 + lane] = pm;
    __syncthreads();
    if (t < 16) {
        float4 a = red[t];
#pragma unroll
        for (int w = 1; w < 4; ++w) {
            float4 o = red[w * 16 + t];
            a.x = fmaxf(a.x, o.x); a.y = fmaxf(a.y, o.y);
            a.z = fmaxf(a.z, o.z); a.w = fmaxf(a.w, o.w);
        }
        float* dst = part + ((size_t)b * 4 + q) * 64 + t * 4;
        dst[0] = a.x; dst[1] = a.y; dst[2] = a.z; dst[3] = a.w;
    }
    __syncthreads();  // drains the part stores (vmcnt(0) before s_barrier)

    // ---- Signal + spin: device-scope, per-batch ----
    if (t == 0) {
        __threadfence();  // make part stores device-visible (L2 writeback)
        __hip_atomic_fetch_add(&cnt[b], 1, __ATOMIC_RELEASE,
                               __HIP_MEMORY_SCOPE_AGENT);
        while (__hip_atomic_load(&cnt[b], __ATOMIC_ACQUIRE,
                                 __HIP_MEMORY_SCOPE_AGENT) < 4)
            __builtin_amdgcn_s_sleep(8);
    }
    __syncthreads();

    // ---- Middle network (redundant per block, deterministic), wave 0 ----
    if (t < 64) {
        const float* pb = part + (size_t)b * 256;
        // device-scope loads: partials may come from another XCD's blocks
        float m = fmaxf(fmaxf(devload(pb + t),       devload(pb + 64 + t)),
                        fmaxf(devload(pb + 128 + t), devload(pb + 192 + t)));
        sm[t] = m;
        const float sgum = gumbel01((unsigned)(b * 64 + t));
        __builtin_amdgcn_wave_barrier();

        // windows: categorical (gumbel) + max + mean; 4-lane shfl argmax,
        // first-max tie-break = JAX semantics
        {
            int w = t >> 2, j = t & 3;
            int hh = 2 * (w >> 2) + (j >> 1), ww = 2 * (w & 3) + (j & 1);
            float v = sm[hh * 8 + ww];
            float wc = bad_val(v) ? EPSV : v;
            float s = wc + sgum;
            int bi = j;
            float bwc = wc;
            float mx = v;
            float ssum = v;
#pragma unroll
            for (int mk = 1; mk <= 2; mk <<= 1) {
                float s2   = __shfl_xor(s, mk, 64);
                int   bi2  = __shfl_xor(bi, mk, 64);
                float bwc2 = __shfl_xor(bwc, mk, 64);
                float mx2  = __shfl_xor(mx, mk, 64);
                float ss2  = __shfl_xor(ssum, mk, 64);
                bool take = (s2 > s) || (s2 == s && bi2 < bi);
                if (take) { s = s2; bi = bi2; bwc = bwc2; }
                mx = fmaxf(mx, mx2);
                ssum += ss2;
            }
            if (j == 0) sa16[w] = 0.1f * bwc + 0.6f * mx + 0.3f * (ssum * 0.25f);
        }
        __builtin_amdgcn_wave_barrier();

        // 3x3 conv (1->1, SAME, no bias) on 4x4, lanes 0..15
        if (t < 16) {
            int i = t >> 2, j = t & 3;
            float acc = 0.0f;
#pragma unroll
            for (int dy = -1; dy <= 1; ++dy) {
                int yy = i + dy;
                if (yy < 0 || yy > 3) continue;
#pragma unroll
                for (int dx = -1; dx <= 1; ++dx) {
                    int xx = j + dx;
                    if (xx < 0 || xx > 3) continue;
                    acc += sa16[yy * 4 + xx] * w11[(dy + 1) * 3 + (dx + 1)];
                }
            }
            sb16[t] = acc;
        }
        __builtin_amdgcn_wave_barrier();

        // bilinear 4x4 -> 8x8 (align_corners=False)
        {
            int y = t >> 3, xx2 = t & 7;
            float sy = (y + 0.5f) * 0.5f - 0.5f;
            float sx = (xx2 + 0.5f) * 0.5f - 0.5f;
            float fy = fminf(fmaxf(sy, 0.0f), 3.0f);
            float fx = fminf(fmaxf(sx, 0.0f), 3.0f);
            int iy0 = (int)floorf(fy); int iy1 = min(iy0 + 1, 3); float ry = fy - (float)iy0;
            int ix0 = (int)floorf(fx); int ix1 = min(ix0 + 1, 3); float rx = fx - (float)ix0;
            float v00 = sb16[iy0 * 4 + ix0], v01 = sb16[iy0 * 4 + ix1];
            float v10 = sb16[iy1 * 4 + ix0], v11 = sb16[iy1 * 4 + ix1];
            float top = v00 * (1.0f - rx) + v01 * rx;
            float bot = v10 * (1.0f - rx) + v11 * rx;
            so2[t] = top * (1.0f - ry) + bot * ry;
        }
        __builtin_amdgcn_wave_barrier();

        // conv5: [2->4] 3x3 SAME + bias + relu on 8x8 (ch0 = m, ch1 = out2)
        {
            int y = t >> 3, x2 = t & 7;
            float a0 = b5[0], a1 = b5[1], a2 = b5[2], a3 = b5[3];
#pragma unroll
            for (int dy = -1; dy <= 1; ++dy) {
                int yy = y + dy;
                if (yy < 0 || yy > 7) continue;
#pragma unroll
                for (int dx = -1; dx <= 1; ++dx) {
                    int xx = x2 + dx;
                    if (xx < 0 || xx > 7) continue;
                    float i0 = sm[yy * 8 + xx];
                    float i1 = so2[yy * 8 + xx];
                    int kk = (dy + 1) * 3 + (dx + 1);
                    a0 += i0 * w5[0 * 18 + kk] + i1 * w5[0 * 18 + 9 + kk];
                    a1 += i0 * w5[1 * 18 + kk] + i1 * w5[1 * 18 + 9 + kk];
                    a2 += i0 * w5[2 * 18 + kk] + i1 * w5[2 * 18 + 9 + kk];
                    a3 += i0 * w5[3 * 18 + kk] + i1 * w5[3 * 18 + 9 + kk];
                }
            }
            shid[0 * 64 + t] = fmaxf(a0, 0.0f);
            shid[1 * 64 + t] = fmaxf(a1, 0.0f);
            shid[2 * 64 + t] = fmaxf(a2, 0.0f);
            shid[3 * 64 + t] = fmaxf(a3, 0.0f);
        }
        __builtin_amdgcn_wave_barrier();

        // conv6: [4->1] 3x3 SAME + bias + sigmoid -> gate (LDS)
        {
            int y = t >> 3, x2 = t & 7;
            float acc = b6[0];
#pragma unroll
            for (int dy = -1; dy <= 1; ++dy) {
                int yy = y + dy;
                if (yy < 0 || yy > 7) continue;
#pragma unroll
                for (int dx = -1; dx <= 1; ++dx) {
                    int xx = x2 + dx;
                    if (xx < 0 || xx > 7) continue;
                    int kk = (dy + 1) * 3 + (dx + 1);
                    int p = yy * 8 + xx;
                    acc += shid[0 * 64 + p] * w6[0 + kk]
                         + shid[1 * 64 + p] * w6[9 + kk]
                         + shid[2 * 64 + p] * w6[18 + kk]
                         + shid[3 * 64 + p] * w6[27 + kk];
                }
            }
            sgate[t] = 1.0f / (1.0f + expf(-acc));
        }
    }
    __syncthreads();

    // ---- Apply: out = relu(x * gate); own quarter is L2-warm; nt stores ----
    const float4 gv = ((const float4*)sgate)[t & 15];
#pragma unroll
    for (int i = 0; i < 16; ++i) {
        float4 v = xq[t + 256 * i];
        f32x4_t o;
        o.x = fmaxf(v.x * gv.x, 0.0f);
        o.y = fmaxf(v.y * gv.y, 0.0f);
        o.z = fmaxf(v.z * gv.z, 0.0f);
        o.w = fmaxf(v.w * gv.w, 0.0f);
        __builtin_nontemporal_store(o, (f32x4_t*)&oq[t + 256 * i]);
    }
}

extern "C" void kernel_launch(void* const* d_in, const int* in_sizes, int n_in,
                              void* d_out, int out_size, void* d_ws, size_t ws_size,
                              hipStream_t stream) {
    const float* x   = (const float*)d_in[0];
    const float* w11 = (const float*)d_in[1];
    const float* w5  = (const float*)d_in[2];
    const float* b5  = (const float*)d_in[3];
    const float* w6  = (const float*)d_in[4];
    const float* b6  = (const float*)d_in[5];
    float* out  = (float*)d_out;

    int B = in_sizes[0] / (C_DIM * HW);  // 512
    int* cnt = (int*)d_ws;                       // B ints (zeroed each launch)
    float* part = (float*)d_ws + 512;            // B*4*64 floats = 512 KB

    hipMemsetAsync(d_ws, 0, (size_t)B * sizeof(int), stream);
    sa_onepass_kernel<<<dim3(B * 4), dim3(256), 0, stream>>>(
        x, w11, w5, b5, w6, b6, out, cnt, part);
}

// Round 10
// 255.286 us; speedup vs baseline: 1.8160x; 1.8160x over previous
//
#include <hip/hip_runtime.h>
#include <math.h>

// x [B=512, C=1024, H=8, W=8] f32. out same shape.
#define C_DIM 1024
#define HW 64
#define NT 1024             // one block per batch, 16 waves
#define F4_PER_BATCH 16384  // C_DIM*HW/4
#define PER_T 16            // F4_PER_BATCH / NT float4 per thread
#define EPSV 1e-8f
#define TINYF 1.17549435e-38f

typedef float f32x4_t __attribute__((ext_vector_type(4)));

// Pin a value into a VGPR: the compiler must treat it as modified, so it
// cannot rematerialize the originating load after the barrier.
__device__ __forceinline__ void keepf(float& v) { asm volatile("" : "+v"(v)); }
__device__ __forceinline__ void keep4(float4& v) {
    keepf(v.x); keepf(v.y); keepf(v.z); keepf(v.w);
}
// consume a value so a warming load cannot be DCE'd
__device__ __forceinline__ void usef(float v) { asm volatile("" :: "v"(v)); }

__device__ __forceinline__ void threefry2x32_01(unsigned x0, unsigned x1,
                                                unsigned& o0, unsigned& o1) {
    const unsigned ks0 = 0u, ks1 = 1u, ks2 = 0x1BD11BDBu; // 0x1BD11BDA ^ 0 ^ 1
    x0 += ks0; x1 += ks1;
#define TF_R(r) { x0 += x1; x1 = (x1 << (r)) | (x1 >> (32 - (r))); x1 ^= x0; }
    TF_R(13) TF_R(15) TF_R(26) TF_R(6)
    x0 += ks1; x1 += ks2 + 1u;
    TF_R(17) TF_R(29) TF_R(16) TF_R(24)
    x0 += ks2; x1 += ks0 + 2u;
    TF_R(13) TF_R(15) TF_R(26) TF_R(6)
    x0 += ks0; x1 += ks1 + 3u;
    TF_R(17) TF_R(29) TF_R(16) TF_R(24)
    x0 += ks1; x1 += ks2 + 4u;
    TF_R(13) TF_R(15) TF_R(26) TF_R(6)
    x0 += ks2; x1 += ks0 + 5u;
#undef TF_R
    o0 = x0; o1 = x1;
}

// jax_threefry_partitionable=True: counter (hi=0, lo=n), out = o0 ^ o1.
__device__ __forceinline__ unsigned jax_random_bits(unsigned n) {
    unsigned o0, o1;
    threefry2x32_01(0u, n, o0, o1);
    return o0 ^ o1;
}

__device__ __forceinline__ bool bad_val(float v) {
    return ((__float_as_uint(v) & 0x7F800000u) == 0x7F800000u) || (v < 0.0f);
}

// ---------------- Fused kernel: x PINNED in registers across gate compute ---
// One block per batch. Phase 1: stream the batch's 256 KiB into 16
// float4/thread registers while reducing the channel max (weights warmed
// under the load latency). Phase 2: wave 0 computes the gate network.
// Phase 3: relu(x*gate) straight from registers -> nt stores.
// Proven-best structure (r4: 85 us kernel, 245.5 us end-to-end). Cross-block
// sync variants (coop r7, spin r9) crater to ~293 us via L2-invalidation
// storms from device-scope acquire fences -- do not reintroduce.
__global__ __launch_bounds__(NT) void sa_fused_kernel(
    const float* __restrict__ x,
    const float* __restrict__ w11,
    const float* __restrict__ w5,
    const float* __restrict__ b5,
    const float* __restrict__ w6,
    const float* __restrict__ b6,
    float* __restrict__ out)
{
    const int b = blockIdx.x;
    const int t = threadIdx.x;

    const float4* __restrict__ xb = (const float4*)x + (size_t)b * F4_PER_BATCH;
    float4* __restrict__ ob = (float4*)out + (size_t)b * F4_PER_BATCH;

    __shared__ float4 red[16 * 16];       // per-wave partial max, 16 hw4 groups
    __shared__ float sm[64];
    __shared__ float sa16[16];
    __shared__ float sb16[16];
    __shared__ float so2[64];
    __shared__ float shid[4 * 64];
    __shared__ __align__(16) float sgate[64];

    // Contiguous streaming read: wave reads 1 KB per instruction.
    // Thread t covers float4 flat indices t + 1024*i -> hw4 group = t&15 fixed.
    float4 xv[PER_T];
    float4 pm = make_float4(-INFINITY, -INFINITY, -INFINITY, -INFINITY);
#pragma unroll
    for (int i = 0; i < PER_T; ++i) {
        xv[i] = xb[t + NT * i];
        pm.x = fmaxf(pm.x, xv[i].x); pm.y = fmaxf(pm.y, xv[i].y);
        pm.z = fmaxf(pm.z, xv[i].z); pm.w = fmaxf(pm.w, xv[i].w);
    }
#pragma unroll
    for (int i = 0; i < PER_T; ++i) keep4(xv[i]);
    if (t == 0) {  // warm the weight cachelines under the streaming latency
        usef(w11[0]); usef(w5[0]); usef(w5[32]); usef(w5[64]);
        usef(b5[0]);  usef(w6[0]); usef(w6[32]); usef(b6[0]);
    }

    // Wave-level reduce over the 4 c-slices within this wave (lanes xor 16, 32).
#pragma unroll
    for (int off = 16; off <= 32; off <<= 1) {
        pm.x = fmaxf(pm.x, __shfl_xor(pm.x, off, 64));
        pm.y = fmaxf(pm.y, __shfl_xor(pm.y, off, 64));
        pm.z = fmaxf(pm.z, __shfl_xor(pm.z, off, 64));
        pm.w = fmaxf(pm.w, __shfl_xor(pm.w, off, 64));
    }
    const int wv = t >> 6, lane = t & 63;
    if (lane < 16) red[wv * 16 + lane] = pm;
    __syncthreads();

    // ---- Middle network: wave 0 only, barrier-free (wave barriers). ----
    if (t < 64) {
        // Final reduce across the 16 wave partials: 4 per lane + 2 shuffles.
        {
            int g = t & 15, set = t >> 4;
            float4 a = red[(set * 4 + 0) * 16 + g];
#pragma unroll
            for (int w = 1; w < 4; ++w) {
                float4 o = red[(set * 4 + w) * 16 + g];
                a.x = fmaxf(a.x, o.x); a.y = fmaxf(a.y, o.y);
                a.z = fmaxf(a.z, o.z); a.w = fmaxf(a.w, o.w);
            }
#pragma unroll
            for (int off = 16; off <= 32; off <<= 1) {
                a.x = fmaxf(a.x, __shfl_xor(a.x, off, 64));
                a.y = fmaxf(a.y, __shfl_xor(a.y, off, 64));
                a.z = fmaxf(a.z, __shfl_xor(a.z, off, 64));
                a.w = fmaxf(a.w, __shfl_xor(a.w, off, 64));
            }
            if (t < 16) {
                sm[t * 4 + 0] = a.x; sm[t * 4 + 1] = a.y;
                sm[t * 4 + 2] = a.z; sm[t * 4 + 3] = a.w;
            }
        }
        __builtin_amdgcn_wave_barrier();

        // Windows: categorical (exact JAX gumbel) + max + mean pooling.
        // One (window, j) pair per lane: 1 threefry + 2 logf each, then a
        // 4-lane shfl argmax (index tie-break = JAX first-max semantics).
        {
            int w = t >> 2, j = t & 3;
            int hh = 2 * (w >> 2) + (j >> 1), ww = 2 * (w & 3) + (j & 1);
            float v = sm[hh * 8 + ww];
            float wc = bad_val(v) ? EPSV : v;
            unsigned bits = jax_random_bits((unsigned)(b * 64 + t));
            float f = __uint_as_float(0x3F800000u | (bits >> 9)) - 1.0f;
            float u = fmaxf(TINYF, f + TINYF);
            float sg = -logf(-logf(u));
            float s = wc + sg;
            int bi = j;
            float bwc = wc;
            float mx = v;
            float ssum = v;
#pragma unroll
            for (int m = 1; m <= 2; m <<= 1) {
                float s2   = __shfl_xor(s, m, 64);
                int   bi2  = __shfl_xor(bi, m, 64);
                float bwc2 = __shfl_xor(bwc, m, 64);
                float mx2  = __shfl_xor(mx, m, 64);
                float ss2  = __shfl_xor(ssum, m, 64);
                bool take = (s2 > s) || (s2 == s && bi2 < bi);
                if (take) { s = s2; bi = bi2; bwc = bwc2; }
                mx = fmaxf(mx, mx2);
                ssum += ss2;
            }
            if (j == 0) sa16[w] = 0.1f * bwc + 0.6f * mx + 0.3f * (ssum * 0.25f);
        }
        __builtin_amdgcn_wave_barrier();

        // 3x3 conv (1->1, SAME, no bias) on 4x4. Lanes 0..15.
        if (t < 16) {
            int i = t >> 2, j = t & 3;
            float acc = 0.0f;
#pragma unroll
            for (int dy = -1; dy <= 1; ++dy) {
                int yy = i + dy;
                if (yy < 0 || yy > 3) continue;
#pragma unroll
                for (int dx = -1; dx <= 1; ++dx) {
                    int xx = j + dx;
                    if (xx < 0 || xx > 3) continue;
                    acc += sa16[yy * 4 + xx] * w11[(dy + 1) * 3 + (dx + 1)];
                }
            }
            sb16[t] = acc;
        }
        __builtin_amdgcn_wave_barrier();

        // Bilinear resize 4x4 -> 8x8 (align_corners=False). All 64 lanes.
        {
            int y = t >> 3, xx2 = t & 7;
            float sy = (y + 0.5f) * 0.5f - 0.5f;
            float sx = (xx2 + 0.5f) * 0.5f - 0.5f;
            float fy = fminf(fmaxf(sy, 0.0f), 3.0f);
            float fx = fminf(fmaxf(sx, 0.0f), 3.0f);
            int iy0 = (int)floorf(fy); int iy1 = min(iy0 + 1, 3); float ry = fy - (float)iy0;
            int ix0 = (int)floorf(fx); int ix1 = min(ix0 + 1, 3); float rx = fx - (float)ix0;
            float v00 = sb16[iy0 * 4 + ix0], v01 = sb16[iy0 * 4 + ix1];
            float v10 = sb16[iy1 * 4 + ix0], v11 = sb16[iy1 * 4 + ix1];
            float top = v00 * (1.0f - rx) + v01 * rx;
            float bot = v10 * (1.0f - rx) + v11 * rx;
            so2[t] = top * (1.0f - ry) + bot * ry;
        }
        __builtin_amdgcn_wave_barrier();

        // conv5: [2->4] 3x3 SAME + bias + relu on 8x8 (ch0 = m, ch1 = out2).
        {
            int y = t >> 3, x2 = t & 7;
            float a0 = b5[0], a1 = b5[1], a2 = b5[2], a3 = b5[3];
#pragma unroll
            for (int dy = -1; dy <= 1; ++dy) {
                int yy = y + dy;
                if (yy < 0 || yy > 7) continue;
#pragma unroll
                for (int dx = -1; dx <= 1; ++dx) {
                    int xx = x2 + dx;
                    if (xx < 0 || xx > 7) continue;
                    float i0 = sm[yy * 8 + xx];
                    float i1 = so2[yy * 8 + xx];
                    int kk = (dy + 1) * 3 + (dx + 1);
                    a0 += i0 * w5[0 * 18 + kk] + i1 * w5[0 * 18 + 9 + kk];
                    a1 += i0 * w5[1 * 18 + kk] + i1 * w5[1 * 18 + 9 + kk];
                    a2 += i0 * w5[2 * 18 + kk] + i1 * w5[2 * 18 + 9 + kk];
                    a3 += i0 * w5[3 * 18 + kk] + i1 * w5[3 * 18 + 9 + kk];
                }
            }
            shid[0 * 64 + t] = fmaxf(a0, 0.0f);
            shid[1 * 64 + t] = fmaxf(a1, 0.0f);
            shid[2 * 64 + t] = fmaxf(a2, 0.0f);
            shid[3 * 64 + t] = fmaxf(a3, 0.0f);
        }
        __builtin_amdgcn_wave_barrier();

        // conv6: [4->1] 3x3 SAME + bias + sigmoid -> gate (LDS).
        {
            int y = t >> 3, x2 = t & 7;
            float acc = b6[0];
#pragma unroll
            for (int dy = -1; dy <= 1; ++dy) {
                int yy = y + dy;
                if (yy < 0 || yy > 7) continue;
#pragma unroll
                for (int dx = -1; dx <= 1; ++dx) {
                    int xx = x2 + dx;
                    if (xx < 0 || xx > 7) continue;
                    int kk = (dy + 1) * 3 + (dx + 1);
                    int p = yy * 8 + xx;
                    acc += shid[0 * 64 + p] * w6[0 + kk]
                         + shid[1 * 64 + p] * w6[9 + kk]
                         + shid[2 * 64 + p] * w6[18 + kk]
                         + shid[3 * 64 + p] * w6[27 + kk];
                }
            }
            sgate[t] = 1.0f / (1.0f + expf(-acc));
        }
    }
    __syncthreads();

    // ---- Apply: out = relu(x * gate), straight from the register cache. ----
    // Non-temporal stores: out is never re-read; keep x LLC-resident instead.
    const float4 gv = ((const float4*)sgate)[t & 15];
#pragma unroll
    for (int i = 0; i < PER_T; ++i) {
        float4 v = xv[i];
        f32x4_t o;
        o.x = fmaxf(v.x * gv.x, 0.0f);
        o.y = fmaxf(v.y * gv.y, 0.0f);
        o.z = fmaxf(v.z * gv.z, 0.0f);
        o.w = fmaxf(v.w * gv.w, 0.0f);
        __builtin_nontemporal_store(o, (f32x4_t*)&ob[t + NT * i]);
    }
}

extern "C" void kernel_launch(void* const* d_in, const int* in_sizes, int n_in,
                              void* d_out, int out_size, void* d_ws, size_t ws_size,
                              hipStream_t stream) {
    const float* x   = (const float*)d_in[0];
    const float* w11 = (const float*)d_in[1];
    const float* w5  = (const float*)d_in[2];
    const float* b5  = (const float*)d_in[3];
    const float* w6  = (const float*)d_in[4];
    const float* b6  = (const float*)d_in[5];
    float* out  = (float*)d_out;

    int B = in_sizes[0] / (C_DIM * HW);  // 512
    sa_fused_kernel<<<dim3(B), dim3(NT), 0, stream>>>(x, w11, w5, b5, w6, b6, out);
}

// Round 11
// 242.728 us; speedup vs baseline: 1.9100x; 1.0517x over previous
//
#include <hip/hip_runtime.h>
#include <math.h>

// x [B=512, C=1024, H=8, W=8] f32. out same shape.
#define C_DIM 1024
#define HW 64
#define NT 1024             // one block per batch, 16 waves
#define F4_PER_BATCH 16384  // C_DIM*HW/4
#define PER_T 16            // F4_PER_BATCH / NT float4 per thread
#define EPSV 1e-8f
#define TINYF 1.17549435e-38f

typedef float f32x4_t __attribute__((ext_vector_type(4)));

// Pin a value into a VGPR: the compiler must treat it as modified, so it
// cannot rematerialize the originating load after the barrier.
// NOTE (r10): do NOT add any extra live values (e.g. weight-warm loads) to
// this kernel -- the register budget is exactly saturated (64 VGPR + 64
// AGPR); anything more spills to scratch (+37 MB writes, +15 us).
__device__ __forceinline__ void keepf(float& v) { asm volatile("" : "+v"(v)); }
__device__ __forceinline__ void keep4(float4& v) {
    keepf(v.x); keepf(v.y); keepf(v.z); keepf(v.w);
}

__device__ __forceinline__ void threefry2x32_01(unsigned x0, unsigned x1,
                                                unsigned& o0, unsigned& o1) {
    const unsigned ks0 = 0u, ks1 = 1u, ks2 = 0x1BD11BDBu; // 0x1BD11BDA ^ 0 ^ 1
    x0 += ks0; x1 += ks1;
#define TF_R(r) { x0 += x1; x1 = (x1 << (r)) | (x1 >> (32 - (r))); x1 ^= x0; }
    TF_R(13) TF_R(15) TF_R(26) TF_R(6)
    x0 += ks1; x1 += ks2 + 1u;
    TF_R(17) TF_R(29) TF_R(16) TF_R(24)
    x0 += ks2; x1 += ks0 + 2u;
    TF_R(13) TF_R(15) TF_R(26) TF_R(6)
    x0 += ks0; x1 += ks1 + 3u;
    TF_R(17) TF_R(29) TF_R(16) TF_R(24)
    x0 += ks1; x1 += ks2 + 4u;
    TF_R(13) TF_R(15) TF_R(26) TF_R(6)
    x0 += ks2; x1 += ks0 + 5u;
#undef TF_R
    o0 = x0; o1 = x1;
}

// jax_threefry_partitionable=True: counter (hi=0, lo=n), out = o0 ^ o1.
__device__ __forceinline__ unsigned jax_random_bits(unsigned n) {
    unsigned o0, o1;
    threefry2x32_01(0u, n, o0, o1);
    return o0 ^ o1;
}

__device__ __forceinline__ bool bad_val(float v) {
    return ((__float_as_uint(v) & 0x7F800000u) == 0x7F800000u) || (v < 0.0f);
}

// ---------------- Fused kernel: x PINNED in registers across gate compute ---
// One block per batch. Phase 1: stream the batch's 256 KiB into 16
// float4/thread registers while reducing the channel max. Phase 2: wave 0
// computes the gate network (gumbel work spread over all 64 lanes).
// Phase 3: relu(x*gate) straight from registers -> nt stores.
// Proven-best structure (r4: 85.2 us kernel, 245.5 us end-to-end).
// Cross-block sync variants (coop r7, spin r9) crater to ~293 us via
// L2-invalidation storms from device-scope acquire fences on non-coherent
// per-XCD L2s -- do not reintroduce.
__global__ __launch_bounds__(NT) void sa_fused_kernel(
    const float* __restrict__ x,
    const float* __restrict__ w11,
    const float* __restrict__ w5,
    const float* __restrict__ b5,
    const float* __restrict__ w6,
    const float* __restrict__ b6,
    float* __restrict__ out)
{
    const int b = blockIdx.x;
    const int t = threadIdx.x;

    const float4* __restrict__ xb = (const float4*)x + (size_t)b * F4_PER_BATCH;
    float4* __restrict__ ob = (float4*)out + (size_t)b * F4_PER_BATCH;

    __shared__ float4 red[16 * 16];       // per-wave partial max, 16 hw4 groups
    __shared__ float sm[64];
    __shared__ float sa16[16];
    __shared__ float sb16[16];
    __shared__ float so2[64];
    __shared__ float shid[4 * 64];
    __shared__ __align__(16) float sgate[64];

    // Contiguous streaming read: wave reads 1 KB per instruction.
    // Thread t covers float4 flat indices t + 1024*i -> hw4 group = t&15 fixed.
    float4 xv[PER_T];
    float4 pm = make_float4(-INFINITY, -INFINITY, -INFINITY, -INFINITY);
#pragma unroll
    for (int i = 0; i < PER_T; ++i) {
        xv[i] = xb[t + NT * i];
        pm.x = fmaxf(pm.x, xv[i].x); pm.y = fmaxf(pm.y, xv[i].y);
        pm.z = fmaxf(pm.z, xv[i].z); pm.w = fmaxf(pm.w, xv[i].w);
    }
#pragma unroll
    for (int i = 0; i < PER_T; ++i) keep4(xv[i]);

    // Wave-level reduce over the 4 c-slices within this wave (lanes xor 16, 32).
#pragma unroll
    for (int off = 16; off <= 32; off <<= 1) {
        pm.x = fmaxf(pm.x, __shfl_xor(pm.x, off, 64));
        pm.y = fmaxf(pm.y, __shfl_xor(pm.y, off, 64));
        pm.z = fmaxf(pm.z, __shfl_xor(pm.z, off, 64));
        pm.w = fmaxf(pm.w, __shfl_xor(pm.w, off, 64));
    }
    const int wv = t >> 6, lane = t & 63;
    if (lane < 16) red[wv * 16 + lane] = pm;
    __syncthreads();

    // ---- Middle network: wave 0 only, barrier-free (wave barriers). ----
    if (t < 64) {
        // Final reduce across the 16 wave partials: 4 per lane + 2 shuffles.
        {
            int g = t & 15, set = t >> 4;
            float4 a = red[(set * 4 + 0) * 16 + g];
#pragma unroll
            for (int w = 1; w < 4; ++w) {
                float4 o = red[(set * 4 + w) * 16 + g];
                a.x = fmaxf(a.x, o.x); a.y = fmaxf(a.y, o.y);
                a.z = fmaxf(a.z, o.z); a.w = fmaxf(a.w, o.w);
            }
#pragma unroll
            for (int off = 16; off <= 32; off <<= 1) {
                a.x = fmaxf(a.x, __shfl_xor(a.x, off, 64));
                a.y = fmaxf(a.y, __shfl_xor(a.y, off, 64));
                a.z = fmaxf(a.z, __shfl_xor(a.z, off, 64));
                a.w = fmaxf(a.w, __shfl_xor(a.w, off, 64));
            }
            if (t < 16) {
                sm[t * 4 + 0] = a.x; sm[t * 4 + 1] = a.y;
                sm[t * 4 + 2] = a.z; sm[t * 4 + 3] = a.w;
            }
        }
        __builtin_amdgcn_wave_barrier();

        // Windows: categorical (exact JAX gumbel) + max + mean pooling.
        // One (window, j) pair per lane: 1 threefry + 2 logf each, then a
        // 4-lane shfl argmax (index tie-break = JAX first-max semantics).
        {
            int w = t >> 2, j = t & 3;
            int hh = 2 * (w >> 2) + (j >> 1), ww = 2 * (w & 3) + (j & 1);
            float v = sm[hh * 8 + ww];
            float wc = bad_val(v) ? EPSV : v;
            unsigned bits = jax_random_bits((unsigned)(b * 64 + t));
            float f = __uint_as_float(0x3F800000u | (bits >> 9)) - 1.0f;
            float u = fmaxf(TINYF, f + TINYF);
            float sg = -logf(-logf(u));
            float s = wc + sg;
            int bi = j;
            float bwc = wc;
            float mx = v;
            float ssum = v;
#pragma unroll
            for (int m = 1; m <= 2; m <<= 1) {
                float s2   = __shfl_xor(s, m, 64);
                int   bi2  = __shfl_xor(bi, m, 64);
                float bwc2 = __shfl_xor(bwc, m, 64);
                float mx2  = __shfl_xor(mx, m, 64);
                float ss2  = __shfl_xor(ssum, m, 64);
                bool take = (s2 > s) || (s2 == s && bi2 < bi);
                if (take) { s = s2; bi = bi2; bwc = bwc2; }
                mx = fmaxf(mx, mx2);
                ssum += ss2;
            }
            if (j == 0) sa16[w] = 0.1f * bwc + 0.6f * mx + 0.3f * (ssum * 0.25f);
        }
        __builtin_amdgcn_wave_barrier();

        // 3x3 conv (1->1, SAME, no bias) on 4x4. Lanes 0..15.
        if (t < 16) {
            int i = t >> 2, j = t & 3;
            float acc = 0.0f;
#pragma unroll
            for (int dy = -1; dy <= 1; ++dy) {
                int yy = i + dy;
                if (yy < 0 || yy > 3) continue;
#pragma unroll
                for (int dx = -1; dx <= 1; ++dx) {
                    int xx = j + dx;
                    if (xx < 0 || xx > 3) continue;
                    acc += sa16[yy * 4 + xx] * w11[(dy + 1) * 3 + (dx + 1)];
                }
            }
            sb16[t] = acc;
        }
        __builtin_amdgcn_wave_barrier();

        // Bilinear resize 4x4 -> 8x8 (align_corners=False). All 64 lanes.
        {
            int y = t >> 3, xx2 = t & 7;
            float sy = (y + 0.5f) * 0.5f - 0.5f;
            float sx = (xx2 + 0.5f) * 0.5f - 0.5f;
            float fy = fminf(fmaxf(sy, 0.0f), 3.0f);
            float fx = fminf(fmaxf(sx, 0.0f), 3.0f);
            int iy0 = (int)floorf(fy); int iy1 = min(iy0 + 1, 3); float ry = fy - (float)iy0;
            int ix0 = (int)floorf(fx); int ix1 = min(ix0 + 1, 3); float rx = fx - (float)ix0;
            float v00 = sb16[iy0 * 4 + ix0], v01 = sb16[iy0 * 4 + ix1];
            float v10 = sb16[iy1 * 4 + ix0], v11 = sb16[iy1 * 4 + ix1];
            float top = v00 * (1.0f - rx) + v01 * rx;
            float bot = v10 * (1.0f - rx) + v11 * rx;
            so2[t] = top * (1.0f - ry) + bot * ry;
        }
        __builtin_amdgcn_wave_barrier();

        // conv5: [2->4] 3x3 SAME + bias + relu on 8x8 (ch0 = m, ch1 = out2).
        {
            int y = t >> 3, x2 = t & 7;
            float a0 = b5[0], a1 = b5[1], a2 = b5[2], a3 = b5[3];
#pragma unroll
            for (int dy = -1; dy <= 1; ++dy) {
                int yy = y + dy;
                if (yy < 0 || yy > 7) continue;
#pragma unroll
                for (int dx = -1; dx <= 1; ++dx) {
                    int xx = x2 + dx;
                    if (xx < 0 || xx > 7) continue;
                    float i0 = sm[yy * 8 + xx];
                    float i1 = so2[yy * 8 + xx];
                    int kk = (dy + 1) * 3 + (dx + 1);
                    a0 += i0 * w5[0 * 18 + kk] + i1 * w5[0 * 18 + 9 + kk];
                    a1 += i0 * w5[1 * 18 + kk] + i1 * w5[1 * 18 + 9 + kk];
                    a2 += i0 * w5[2 * 18 + kk] + i1 * w5[2 * 18 + 9 + kk];
                    a3 += i0 * w5[3 * 18 + kk] + i1 * w5[3 * 18 + 9 + kk];
                }
            }
            shid[0 * 64 + t] = fmaxf(a0, 0.0f);
            shid[1 * 64 + t] = fmaxf(a1, 0.0f);
            shid[2 * 64 + t] = fmaxf(a2, 0.0f);
            shid[3 * 64 + t] = fmaxf(a3, 0.0f);
        }
        __builtin_amdgcn_wave_barrier();

        // conv6: [4->1] 3x3 SAME + bias + sigmoid -> gate (LDS).
        {
            int y = t >> 3, x2 = t & 7;
            float acc = b6[0];
#pragma unroll
            for (int dy = -1; dy <= 1; ++dy) {
                int yy = y + dy;
                if (yy < 0 || yy > 7) continue;
#pragma unroll
                for (int dx = -1; dx <= 1; ++dx) {
                    int xx = x2 + dx;
                    if (xx < 0 || xx > 7) continue;
                    int kk = (dy + 1) * 3 + (dx + 1);
                    int p = yy * 8 + xx;
                    acc += shid[0 * 64 + p] * w6[0 + kk]
                         + shid[1 * 64 + p] * w6[9 + kk]
                         + shid[2 * 64 + p] * w6[18 + kk]
                         + shid[3 * 64 + p] * w6[27 + kk];
                }
            }
            sgate[t] = 1.0f / (1.0f + expf(-acc));
        }
    }
    __syncthreads();

    // ---- Apply: out = relu(x * gate), straight from the register cache. ----
    // Non-temporal stores: out is never re-read; keep x LLC-resident instead.
    const float4 gv = ((const float4*)sgate)[t & 15];
#pragma unroll
    for (int i = 0; i < PER_T; ++i) {
        float4 v = xv[i];
        f32x4_t o;
        o.x = fmaxf(v.x * gv.x, 0.0f);
        o.y = fmaxf(v.y * gv.y, 0.0f);
        o.z = fmaxf(v.z * gv.z, 0.0f);
        o.w = fmaxf(v.w * gv.w, 0.0f);
        __builtin_nontemporal_store(o, (f32x4_t*)&ob[t + NT * i]);
    }
}

extern "C" void kernel_launch(void* const* d_in, const int* in_sizes, int n_in,
                              void* d_out, int out_size, void* d_ws, size_t ws_size,
                              hipStream_t stream) {
    const float* x   = (const float*)d_in[0];
    const float* w11 = (const float*)d_in[1];
    const float* w5  = (const float*)d_in[2];
    const float* b5  = (const float*)d_in[3];
    const float* w6  = (const float*)d_in[4];
    const float* b6  = (const float*)d_in[5];
    float* out  = (float*)d_out;

    int B = in_sizes[0] / (C_DIM * HW);  // 512
    sa_fused_kernel<<<dim3(B), dim3(NT), 0, stream>>>(x, w11, w5, b5, w6, b6, out);
}